// Round 10
// baseline (129.396 us; speedup 1.0000x reference)
//
#include <hip/hip_runtime.h>
#include <hip/hip_bf16.h>

// ROIAlign: feat [B=4, C=256, H=200, W=304] fp32, rois [N=1024,4] fp32,
// roibatches [N] int32 -> out [N, C, 7, 7] fp32.  POOL=7, SCALE=0.25, SAMP=2.
//
// K0: stable counting sort of roi ids by batch -> perm.
// K1: NCHW fp32 -> [B][16cg][H][W][16ch] bf16 in d_ws (124 MB).
// K2: grid = cghalf*(N*8) + rank*8 + cg8  (XCD k == cg8 k); per-XCD hot set
//     = one (batch,cg16) slice = 1.95 MB < 4 MB L2 -> inter-roi reuse L2-hit.
//     Block (256thr) = one (roi,cg16): wave = 16 bins, lane owns 4ch (uint2).
//     x_lo/x_hi corners are adjacent 32B halves -> shared 64B lines.

#define POOL 7
constexpr int Bc = 4;
constexpr int Cc = 256;
constexpr int Hc = 200;
constexpr int Wc = 304;
constexpr int HWc = Hc * Wc;           // 60800
constexpr float SCALEc = 0.25f;

static __device__ __forceinline__ float bf16_lo(unsigned u) {
    u <<= 16;
    return __builtin_bit_cast(float, u);
}
static __device__ __forceinline__ float bf16_hi(unsigned u) {
    u &= 0xFFFF0000u;
    return __builtin_bit_cast(float, u);
}
static __device__ __forceinline__ unsigned pack_bf16(float f0, float f1) {
    unsigned u0 = (unsigned)__hip_bfloat16_raw(__float2bfloat16(f0)).x;
    unsigned u1 = (unsigned)__hip_bfloat16_raw(__float2bfloat16(f1)).x;
    return u0 | (u1 << 16);
}

// ---------------- K0: stable counting sort of roi ids by batch ----------------
__global__ __launch_bounds__(1024) void sort_rois_by_batch(
    const int* __restrict__ rb, int* __restrict__ perm, int N)
{
    __shared__ int wave_cnt[16][4];
    __shared__ int bucket_base[4];
    int t    = threadIdx.x;
    int w    = t >> 6;
    int lane = t & 63;
    int b    = (t < N) ? rb[t] : -1;

    unsigned long long m[4];
#pragma unroll
    for (int k = 0; k < 4; ++k) m[k] = __ballot(b == k);
    if (lane == 0) {
#pragma unroll
        for (int k = 0; k < 4; ++k) wave_cnt[w][k] = __popcll(m[k]);
    }
    __syncthreads();
    if (t == 0) {
        int base = 0;
#pragma unroll
        for (int k = 0; k < 4; ++k) {
            int tot = 0;
            for (int ww = 0; ww < 16; ++ww) tot += wave_cnt[ww][k];
            bucket_base[k] = base;
            base += tot;
        }
    }
    __syncthreads();
    if (b >= 0) {
        int rank = bucket_base[b];
        for (int ww = 0; ww < w; ++ww) rank += wave_cnt[ww][b];
        unsigned long long lt = (lane == 0) ? 0ULL : (~0ULL >> (64 - lane));
        rank += __popcll(m[b] & lt);
        perm[rank] = t;
    }
}

// ---------------- K1: NCHW fp32 -> [B][16][HW][16] bf16 ----------------
// Tile: 128 channels x 64 HW positions. Block (64,4).
__global__ __launch_bounds__(256) void nchw_to_cg16_bf16(
    const float* __restrict__ in, ushort* __restrict__ outp)
{
    __shared__ float tile[128][65];
    int b  = blockIdx.z;
    int p0 = blockIdx.x * 64;    // HW origin
    int c0 = blockIdx.y * 128;   // C origin (0 or 128)
    int tx = threadIdx.x;        // 0..63
    int ty = threadIdx.y;        // 0..3

    const float* src = in + ((size_t)b * Cc + c0) * (size_t)HWc + p0;
#pragma unroll
    for (int k = 0; k < 32; ++k) {
        int c = ty + 4 * k;
        tile[c][tx ^ ((c >> 5) & 3)] = src[(size_t)c * HWc + tx];
    }
    __syncthreads();

    int t       = ty * 64 + tx;  // 0..255
    int cgsel   = t >> 7;        // 0,1
    int rr      = t & 127;
    int p       = rr >> 1;       // 0..63
    int halfsel = rr & 1;        // ch8 = halfsel*8
#pragma unroll
    for (int cgl = 0; cgl < 4; ++cgl) {
        int cgrel = cgl * 2 + cgsel;          // 0..7 (16ch group within the 128)
        int cbase = cgrel * 16 + halfsel * 8; // relative channel base
        unsigned u[4];
#pragma unroll
        for (int j = 0; j < 4; ++j) {
            int ce = cbase + 2 * j;
            int co = ce + 1;
            float f0 = tile[ce][p ^ ((ce >> 5) & 3)];
            float f1 = tile[co][p ^ ((co >> 5) & 3)];
            u[j] = pack_bf16(f0, f1);
        }
        int cg16 = (c0 >> 4) + cgrel;         // 0..15
        size_t d = (((size_t)(b * 16 + cg16)) * HWc + p0 + p) * 16 + halfsel * 8;
        *(uint4*)(outp + d) = make_uint4(u[0], u[1], u[2], u[3]);
    }
}

// ---------------- K2: gather + pool, block = (roi rank, cg16) ----------------
__global__ __launch_bounds__(256, 8) void roialign_gather_cg16(
    const ushort* __restrict__ f,      // [B][16][HW][16] bf16
    const float*  __restrict__ rois,
    const int*    __restrict__ rb,
    const int*    __restrict__ perm,
    float*        __restrict__ out,
    int N)
{
    __shared__ float stage[16 * 50];   // [ch][bin], row stride 50

    int bid    = blockIdx.x;
    int half8  = bid / (N * 8);        // 0,1 (cg-half major => per-XCD 1.95MB slice)
    int rem    = bid - half8 * (N * 8);
    int r      = rem >> 3;             // sorted rank
    int cg8    = rem & 7;              // == XCD (round-robin dispatch)
    int cg     = half8 * 8 + cg8;      // 0..15
    int n      = perm[r];
    int t      = threadIdx.x;          // 0..255
    int w      = t >> 6;               // wave 0..3
    int lane   = t & 63;
    int pixslot= lane >> 2;            // 0..15 -> bin = w*16 + pixslot
    int cs     = lane & 3;             // channels cs*4 .. cs*4+3
    int bin    = w * 16 + pixslot;     // 0..63

    float x1 = rois[n * 4 + 0] * SCALEc;
    float y1 = rois[n * 4 + 1] * SCALEc;
    float x2 = rois[n * 4 + 2] * SCALEc;
    float y2 = rois[n * 4 + 3] * SCALEc;
    int   b  = rb[n];

    float roi_w = fmaxf(x2 - x1, 1.0f);
    float roi_h = fmaxf(y2 - y1, 1.0f);
    float bin_w = roi_w * (1.0f / POOL);
    float bin_h = roi_h * (1.0f / POOL);

    // cg slice base; one pixel = 4 uint2 (16 bf16 ch)
    const uint2* fb = (const uint2*)(f + (size_t)(b * 16 + cg) * ((size_t)HWc * 16));

    if (bin < 49) {
        int ph = bin / POOL;
        int pw = bin - ph * POOL;

        unsigned yrow[2][2];  float wy[2][2];
#pragma unroll
        for (int iy = 0; iy < 2; ++iy) {
            float y  = y1 + ((float)ph + ((float)iy + 0.5f) * 0.5f) * bin_h;
            bool  vy = (y >= -1.0f) && (y <= (float)Hc);
            float yc = fminf(fmaxf(y, 0.0f), (float)(Hc - 1));
            int   y_lo = (int)floorf(yc);
            int   y_hi = min(y_lo + 1, Hc - 1);
            float ly = yc - (float)y_lo;
            yrow[iy][0] = (unsigned)(y_lo * Wc);
            yrow[iy][1] = (unsigned)(y_hi * Wc);
            wy[iy][0] = vy ? (1.0f - ly) : 0.0f;
            wy[iy][1] = vy ? ly : 0.0f;
        }
        unsigned xo[2][2];  float wx[2][2];
#pragma unroll
        for (int ix = 0; ix < 2; ++ix) {
            float x  = x1 + ((float)pw + ((float)ix + 0.5f) * 0.5f) * bin_w;
            bool  vx = (x >= -1.0f) && (x <= (float)Wc);
            float xc = fminf(fmaxf(x, 0.0f), (float)(Wc - 1));
            int   x_lo = (int)floorf(xc);
            int   x_hi = min(x_lo + 1, Wc - 1);
            float lx = xc - (float)x_lo;
            xo[ix][0] = (unsigned)x_lo;
            xo[ix][1] = (unsigned)x_hi;
            wx[ix][0] = vx ? (1.0f - lx) : 0.0f;
            wx[ix][1] = vx ? lx : 0.0f;
        }

        float acc0 = 0.f, acc1 = 0.f, acc2 = 0.f, acc3 = 0.f;
#pragma unroll
        for (int iy = 0; iy < 2; ++iy) {
            // batch this y-sample's 8 corner loads (uint2 each)
            uint2 v[8];
#pragma unroll
            for (int q = 0; q < 8; ++q) {
                int yl = q >> 2, ix = (q >> 1) & 1, xl = q & 1;
                unsigned pix = yrow[iy][yl] + xo[ix][xl];
                v[q] = fb[(size_t)pix * 4u + (unsigned)cs];
            }
#pragma unroll
            for (int q = 0; q < 8; ++q) {
                int yl = q >> 2, ix = (q >> 1) & 1, xl = q & 1;
                float wq = wy[iy][yl] * wx[ix][xl];
                acc0 = fmaf(wq, bf16_lo(v[q].x), acc0);
                acc1 = fmaf(wq, bf16_hi(v[q].x), acc1);
                acc2 = fmaf(wq, bf16_lo(v[q].y), acc2);
                acc3 = fmaf(wq, bf16_hi(v[q].y), acc3);
            }
        }
        int ch = cs * 4;
        stage[(ch + 0) * 50 + bin] = acc0 * 0.25f;
        stage[(ch + 1) * 50 + bin] = acc1 * 0.25f;
        stage[(ch + 2) * 50 + bin] = acc2 * 0.25f;
        stage[(ch + 3) * 50 + bin] = acc3 * 0.25f;
    }
    __syncthreads();

    // coalesced write of this (roi, cg16) 784-float contiguous chunk
    float* obase = out + (size_t)n * (Cc * POOL * POOL) + (size_t)cg * (16 * POOL * POOL);
#pragma unroll
    for (int k = 0; k < 4; ++k) {
        int flat = t + 256 * k;            // c*49 + bin, c in [0,16)
        if (flat < 16 * POOL * POOL) {
            int c  = flat / 49;
            int bn = flat - c * 49;
            obase[flat] = stage[c * 50 + bn];
        }
    }
}

// ---------------- Fallback (no workspace): direct NCHW kernel ----------------
__global__ __launch_bounds__(256) void roialign_fwd(
    const float* __restrict__ feat,
    const float* __restrict__ rois,
    const int* __restrict__ roibatches,
    float* __restrict__ out,
    int total)
{
    int tid = blockIdx.x * blockDim.x + threadIdx.x;
    if (tid >= total) return;
    int n   = tid / (Cc * POOL * POOL);
    int rem = tid % (Cc * POOL * POOL);
    int c   = rem / (POOL * POOL);
    int bin = rem % (POOL * POOL);
    int ph  = bin / POOL;
    int pw  = bin % POOL;

    float x1 = rois[n * 4 + 0] * SCALEc;
    float y1 = rois[n * 4 + 1] * SCALEc;
    float x2 = rois[n * 4 + 2] * SCALEc;
    float y2 = rois[n * 4 + 3] * SCALEc;
    int   b  = roibatches[n];

    float roi_w = fmaxf(x2 - x1, 1.0f);
    float roi_h = fmaxf(y2 - y1, 1.0f);
    float bin_w = roi_w * (1.0f / POOL);
    float bin_h = roi_h * (1.0f / POOL);

    const float* fp = feat + (size_t)(b * Cc + c) * (size_t)HWc;

    float acc = 0.0f;
#pragma unroll
    for (int iy = 0; iy < 2; ++iy) {
        float y  = y1 + ((float)ph + ((float)iy + 0.5f) * 0.5f) * bin_h;
        bool  vy = (y >= -1.0f) && (y <= (float)Hc);
        float yc = fminf(fmaxf(y, 0.0f), (float)(Hc - 1));
        int   y_lo = (int)floorf(yc);
        int   y_hi = min(y_lo + 1, Hc - 1);
        float ly = yc - (float)y_lo;
        float hy = 1.0f - ly;
        float wyl = vy ? hy : 0.0f;
        float wyh = vy ? ly : 0.0f;
        const float* row_lo = fp + (size_t)y_lo * Wc;
        const float* row_hi = fp + (size_t)y_hi * Wc;
#pragma unroll
        for (int ix = 0; ix < 2; ++ix) {
            float x  = x1 + ((float)pw + ((float)ix + 0.5f) * 0.5f) * bin_w;
            bool  vx = (x >= -1.0f) && (x <= (float)Wc);
            float xc = fminf(fmaxf(x, 0.0f), (float)(Wc - 1));
            int   x_lo = (int)floorf(xc);
            int   x_hi = min(x_lo + 1, Wc - 1);
            float lx = xc - (float)x_lo;
            float hx = 1.0f - lx;
            float wxl = vx ? hx : 0.0f;
            float wxh = vx ? lx : 0.0f;
            acc += wyl * (wxl * row_lo[x_lo] + wxh * row_lo[x_hi])
                 + wyh * (wxl * row_hi[x_lo] + wxh * row_hi[x_hi]);
        }
    }
    out[tid] = acc * 0.25f;
}

extern "C" void kernel_launch(void* const* d_in, const int* in_sizes, int n_in,
                              void* d_out, int out_size, void* d_ws, size_t ws_size,
                              hipStream_t stream)
{
    const float* feat       = (const float*)d_in[0];
    const float* rois       = (const float*)d_in[1];
    const int*   roibatches = (const int*)d_in[2];
    float*       out        = (float*)d_out;
    int N = in_sizes[1] / 4;

    size_t need_copy = (size_t)Bc * HWc * Cc * sizeof(ushort);  // ~124.5 MB
    size_t need = need_copy + (size_t)N * sizeof(int);
    if (ws_size >= need && N <= 1024) {
        ushort* fbh  = (ushort*)d_ws;
        int*    perm = (int*)((char*)d_ws + need_copy);

        sort_rois_by_batch<<<1, 1024, 0, stream>>>(roibatches, perm, N);

        dim3 tgrid(HWc / 64, Cc / 128, Bc);
        dim3 tblock(64, 4);
        nchw_to_cg16_bf16<<<tgrid, tblock, 0, stream>>>(feat, fbh);

        roialign_gather_cg16<<<2 * N * 8, 256, 0, stream>>>(
            fbh, rois, roibatches, perm, out, N);
    } else {
        int total = out_size;
        roialign_fwd<<<(total + 255) / 256, 256, 0, stream>>>(
            feat, rois, roibatches, out, total);
    }
}

// Round 11
// 122.682 us; speedup vs baseline: 1.0547x; 1.0547x over previous
//
#include <hip/hip_runtime.h>
#include <hip/hip_bf16.h>

// ROIAlign: feat [B=4, C=256, H=200, W=304] fp32, rois [N=1024,4] fp32,
// roibatches [N] int32 -> out [N, C, 7, 7] fp32.  POOL=7, SCALE=0.25, SAMP=2.
//
// FINAL (round-9 optimum, 121 us):
// K0: stable counting sort of roi ids by batch -> perm.
// K1: NCHW fp32 -> [B][8cg][H][W][32ch] bf16 in d_ws (124 MB).
// K2: grid = rank*8+cg, cg = bid&7 -> XCD k only touches channel-group k.
//     Block (512thr) = one (roi, cg): wave = 8 bins (lane-octet each),
//     lane owns 4ch (uint2 corner loads; 8x64B = 512B/instr, full lines).
//
// Roofline: total ~770 MB moved at ~6.3 TB/s flat beyond-L2 bandwidth
// -> ~121 us. Compulsory two-pass floor is 548 MB (~87 us); the gap is
// K2's inter-roi pixel re-fetch (3.3x reuse, working set > 4MB/XCD L2),
// shown irreducible across batch-sort/y-sort/XCD-chunk/cg32/cg16 variants.

#define POOL 7
constexpr int Bc = 4;
constexpr int Cc = 256;
constexpr int Hc = 200;
constexpr int Wc = 304;
constexpr int HWc = Hc * Wc;           // 60800
constexpr float SCALEc = 0.25f;

static __device__ __forceinline__ float bf16_lo(unsigned u) {
    u <<= 16;
    return __builtin_bit_cast(float, u);
}
static __device__ __forceinline__ float bf16_hi(unsigned u) {
    u &= 0xFFFF0000u;
    return __builtin_bit_cast(float, u);
}
static __device__ __forceinline__ unsigned pack_bf16(float f0, float f1) {
    unsigned u0 = (unsigned)__hip_bfloat16_raw(__float2bfloat16(f0)).x;
    unsigned u1 = (unsigned)__hip_bfloat16_raw(__float2bfloat16(f1)).x;
    return u0 | (u1 << 16);
}

// ---------------- K0: stable counting sort of roi ids by batch ----------------
__global__ __launch_bounds__(1024) void sort_rois_by_batch(
    const int* __restrict__ rb, int* __restrict__ perm, int N)
{
    __shared__ int wave_cnt[16][4];
    __shared__ int bucket_base[4];
    int t    = threadIdx.x;
    int w    = t >> 6;
    int lane = t & 63;
    int b    = (t < N) ? rb[t] : -1;

    unsigned long long m[4];
#pragma unroll
    for (int k = 0; k < 4; ++k) m[k] = __ballot(b == k);
    if (lane == 0) {
#pragma unroll
        for (int k = 0; k < 4; ++k) wave_cnt[w][k] = __popcll(m[k]);
    }
    __syncthreads();
    if (t == 0) {
        int base = 0;
#pragma unroll
        for (int k = 0; k < 4; ++k) {
            int tot = 0;
            for (int ww = 0; ww < 16; ++ww) tot += wave_cnt[ww][k];
            bucket_base[k] = base;
            base += tot;
        }
    }
    __syncthreads();
    if (b >= 0) {
        int rank = bucket_base[b];
        for (int ww = 0; ww < w; ++ww) rank += wave_cnt[ww][b];
        unsigned long long lt = (lane == 0) ? 0ULL : (~0ULL >> (64 - lane));
        rank += __popcll(m[b] & lt);
        perm[rank] = t;
    }
}

// ---------------- K1: NCHW fp32 -> [B][8][HW][32] bf16 ----------------
// Tile: 128 channels x 64 HW positions. Block (64,4).
__global__ __launch_bounds__(256) void nchw_to_cg32_bf16(
    const float* __restrict__ in, ushort* __restrict__ outp)
{
    __shared__ float tile[128][65];
    int b  = blockIdx.z;
    int p0 = blockIdx.x * 64;    // HW origin
    int c0 = blockIdx.y * 128;   // C origin (0 or 128)
    int tx = threadIdx.x;        // 0..63
    int ty = threadIdx.y;        // 0..3

    const float* src = in + ((size_t)b * Cc + c0) * (size_t)HWc + p0;
#pragma unroll
    for (int k = 0; k < 32; ++k) {
        int c = ty + 4 * k;
        tile[c][tx ^ ((c >> 5) & 3)] = src[(size_t)c * HWc + tx];
    }
    __syncthreads();

    int t   = ty * 64 + tx;      // 0..255
    int ch8 = (t & 3) * 8;       // 0,8,16,24 within the 32-ch group
    int p   = t >> 2;            // 0..63
#pragma unroll
    for (int cgl = 0; cgl < 4; ++cgl) {
        int cg = (c0 >> 5) + cgl;           // 0..7
        unsigned u[4];
#pragma unroll
        for (int j = 0; j < 4; ++j) {
            int ce = cgl * 32 + ch8 + 2 * j;
            int co = ce + 1;
            float f0 = tile[ce][p ^ ((ce >> 5) & 3)];
            float f1 = tile[co][p ^ ((co >> 5) & 3)];
            u[j] = pack_bf16(f0, f1);
        }
        size_t d = ((size_t)(b * 8 + cg) * HWc + p0 + p) * 32 + ch8;
        *(uint4*)(outp + d) = make_uint4(u[0], u[1], u[2], u[3]);
    }
}

// ---------------- K2: gather + pool, block = (roi rank, cgroup) ----------------
__global__ __launch_bounds__(512, 8) void roialign_gather_cg(
    const ushort* __restrict__ f,      // [B][8][HW][32] bf16
    const float*  __restrict__ rois,
    const int*    __restrict__ rb,
    const int*    __restrict__ perm,
    float*        __restrict__ out)
{
    __shared__ float stage[32 * 50];   // [ch][bin], row stride 50

    int bid  = blockIdx.x;
    int cg   = bid & 7;            // == XCD (round-robin dispatch)
    int r    = bid >> 3;           // sorted rank
    int n    = perm[r];
    int t    = threadIdx.x;        // 0..511
    int w    = t >> 6;             // wave 0..7
    int lane = t & 63;
    int oct  = lane >> 3;          // 0..7 -> bin = w*8 + oct
    int cs   = lane & 7;           // uint2 slot: channels cs*4 .. cs*4+3
    int bin  = w * 8 + oct;        // 0..63

    float x1 = rois[n * 4 + 0] * SCALEc;
    float y1 = rois[n * 4 + 1] * SCALEc;
    float x2 = rois[n * 4 + 2] * SCALEc;
    float y2 = rois[n * 4 + 3] * SCALEc;
    int   b  = rb[n];

    float roi_w = fmaxf(x2 - x1, 1.0f);
    float roi_h = fmaxf(y2 - y1, 1.0f);
    float bin_w = roi_w * (1.0f / POOL);
    float bin_h = roi_h * (1.0f / POOL);

    // cg slice base; one pixel = 8 uint2 (32 bf16 ch)
    const uint2* fb = (const uint2*)(f + (size_t)(b * 8 + cg) * ((size_t)HWc * 32));

    if (bin < 49) {
        int ph = (bin * 9363) >> 16;   // bin / 7
        int pw = bin - ph * 7;

        unsigned yrow[2][2];  float wy[2][2];
#pragma unroll
        for (int iy = 0; iy < 2; ++iy) {
            float y  = y1 + ((float)ph + ((float)iy + 0.5f) * 0.5f) * bin_h;
            bool  vy = (y >= -1.0f) && (y <= (float)Hc);
            float yc = fminf(fmaxf(y, 0.0f), (float)(Hc - 1));
            int   y_lo = (int)floorf(yc);
            int   y_hi = min(y_lo + 1, Hc - 1);
            float ly = yc - (float)y_lo;
            yrow[iy][0] = (unsigned)(y_lo * Wc);
            yrow[iy][1] = (unsigned)(y_hi * Wc);
            wy[iy][0] = vy ? (1.0f - ly) : 0.0f;
            wy[iy][1] = vy ? ly : 0.0f;
        }
        unsigned xo[2][2];  float wx[2][2];
#pragma unroll
        for (int ix = 0; ix < 2; ++ix) {
            float x  = x1 + ((float)pw + ((float)ix + 0.5f) * 0.5f) * bin_w;
            bool  vx = (x >= -1.0f) && (x <= (float)Wc);
            float xc = fminf(fmaxf(x, 0.0f), (float)(Wc - 1));
            int   x_lo = (int)floorf(xc);
            int   x_hi = min(x_lo + 1, Wc - 1);
            float lx = xc - (float)x_lo;
            xo[ix][0] = (unsigned)x_lo;
            xo[ix][1] = (unsigned)x_hi;
            wx[ix][0] = vx ? (1.0f - lx) : 0.0f;
            wx[ix][1] = vx ? lx : 0.0f;
        }

        float acc0 = 0.f, acc1 = 0.f, acc2 = 0.f, acc3 = 0.f;
#pragma unroll
        for (int iy = 0; iy < 2; ++iy) {
            // batch this y-sample's 8 corner loads (uint2 each, 64B/pixel lines)
            uint2 v[8];
#pragma unroll
            for (int q = 0; q < 8; ++q) {
                int yl = q >> 2, ix = (q >> 1) & 1, xl = q & 1;
                unsigned pix = yrow[iy][yl] + xo[ix][xl];
                v[q] = fb[(size_t)pix * 8u + (unsigned)cs];
            }
#pragma unroll
            for (int q = 0; q < 8; ++q) {
                int yl = q >> 2, ix = (q >> 1) & 1, xl = q & 1;
                float wq = wy[iy][yl] * wx[ix][xl];
                acc0 = fmaf(wq, bf16_lo(v[q].x), acc0);
                acc1 = fmaf(wq, bf16_hi(v[q].x), acc1);
                acc2 = fmaf(wq, bf16_lo(v[q].y), acc2);
                acc3 = fmaf(wq, bf16_hi(v[q].y), acc3);
            }
        }
        int ch = cs * 4;
        stage[(ch + 0) * 50 + bin] = acc0 * 0.25f;
        stage[(ch + 1) * 50 + bin] = acc1 * 0.25f;
        stage[(ch + 2) * 50 + bin] = acc2 * 0.25f;
        stage[(ch + 3) * 50 + bin] = acc3 * 0.25f;
    }
    __syncthreads();

    // coalesced write of this (roi, cg) 1568-float contiguous chunk
    float* obase = out + (size_t)n * (Cc * POOL * POOL) + (size_t)cg * (32 * POOL * POOL);
#pragma unroll
    for (int k = 0; k < 4; ++k) {
        int flat = t + 512 * k;            // c*49 + bin, c in [0,32)
        if (flat < 32 * POOL * POOL) {
            unsigned c    = ((unsigned)flat * 42800u) >> 21;   // flat / 49
            unsigned bn   = (unsigned)flat - c * 49u;
            obase[flat] = stage[c * 50 + bn];
        }
    }
}

// ---------------- Fallback (no workspace): direct NCHW kernel ----------------
__global__ __launch_bounds__(256) void roialign_fwd(
    const float* __restrict__ feat,
    const float* __restrict__ rois,
    const int* __restrict__ roibatches,
    float* __restrict__ out,
    int total)
{
    int tid = blockIdx.x * blockDim.x + threadIdx.x;
    if (tid >= total) return;
    int n   = tid / (Cc * POOL * POOL);
    int rem = tid % (Cc * POOL * POOL);
    int c   = rem / (POOL * POOL);
    int bin = rem % (POOL * POOL);
    int ph  = bin / POOL;
    int pw  = bin % POOL;

    float x1 = rois[n * 4 + 0] * SCALEc;
    float y1 = rois[n * 4 + 1] * SCALEc;
    float x2 = rois[n * 4 + 2] * SCALEc;
    float y2 = rois[n * 4 + 3] * SCALEc;
    int   b  = roibatches[n];

    float roi_w = fmaxf(x2 - x1, 1.0f);
    float roi_h = fmaxf(y2 - y1, 1.0f);
    float bin_w = roi_w * (1.0f / POOL);
    float bin_h = roi_h * (1.0f / POOL);

    const float* fp = feat + (size_t)(b * Cc + c) * (size_t)HWc;

    float acc = 0.0f;
#pragma unroll
    for (int iy = 0; iy < 2; ++iy) {
        float y  = y1 + ((float)ph + ((float)iy + 0.5f) * 0.5f) * bin_h;
        bool  vy = (y >= -1.0f) && (y <= (float)Hc);
        float yc = fminf(fmaxf(y, 0.0f), (float)(Hc - 1));
        int   y_lo = (int)floorf(yc);
        int   y_hi = min(y_lo + 1, Hc - 1);
        float ly = yc - (float)y_lo;
        float hy = 1.0f - ly;
        float wyl = vy ? hy : 0.0f;
        float wyh = vy ? ly : 0.0f;
        const float* row_lo = fp + (size_t)y_lo * Wc;
        const float* row_hi = fp + (size_t)y_hi * Wc;
#pragma unroll
        for (int ix = 0; ix < 2; ++ix) {
            float x  = x1 + ((float)pw + ((float)ix + 0.5f) * 0.5f) * bin_w;
            bool  vx = (x >= -1.0f) && (x <= (float)Wc);
            float xc = fminf(fmaxf(x, 0.0f), (float)(Wc - 1));
            int   x_lo = (int)floorf(xc);
            int   x_hi = min(x_lo + 1, Wc - 1);
            float lx = xc - (float)x_lo;
            float hx = 1.0f - lx;
            float wxl = vx ? hx : 0.0f;
            float wxh = vx ? lx : 0.0f;
            acc += wyl * (wxl * row_lo[x_lo] + wxh * row_lo[x_hi])
                 + wyh * (wxl * row_hi[x_lo] + wxh * row_hi[x_hi]);
        }
    }
    out[tid] = acc * 0.25f;
}

extern "C" void kernel_launch(void* const* d_in, const int* in_sizes, int n_in,
                              void* d_out, int out_size, void* d_ws, size_t ws_size,
                              hipStream_t stream)
{
    const float* feat       = (const float*)d_in[0];
    const float* rois       = (const float*)d_in[1];
    const int*   roibatches = (const int*)d_in[2];
    float*       out        = (float*)d_out;
    int N = in_sizes[1] / 4;

    size_t need_copy = (size_t)Bc * HWc * Cc * sizeof(ushort);  // ~124.5 MB
    size_t need = need_copy + (size_t)N * sizeof(int);
    if (ws_size >= need && N <= 1024) {
        ushort* fbh  = (ushort*)d_ws;
        int*    perm = (int*)((char*)d_ws + need_copy);

        sort_rois_by_batch<<<1, 1024, 0, stream>>>(roibatches, perm, N);

        dim3 tgrid(HWc / 64, Cc / 128, Bc);
        dim3 tblock(64, 4);
        nchw_to_cg32_bf16<<<tgrid, tblock, 0, stream>>>(feat, fbh);

        roialign_gather_cg<<<N * 8, 512, 0, stream>>>(fbh, rois, roibatches, perm, out);
    } else {
        int total = out_size;
        roialign_fwd<<<(total + 255) / 256, 256, 0, stream>>>(
            feat, rois, roibatches, out, total);
    }
}